// Round 9
// baseline (26.220 us; speedup 1.0000x reference)
//
#include <hip/hip_runtime.h>

#define Bq 32
#define Jq 16
#define Hq 256
#define Wq 256
#define Cn 7
#define HW (Hq * Wq)          // 65536 per (b,j)
#define NBJ (Bq * Jq)         // 512 blocks, one per (b,j)
#define TPB 256

typedef float f32x4 __attribute__((ext_vector_type(4)));

__global__ __launch_bounds__(TPB) void labelloss_argmax_kernel(
    const float* __restrict__ pred,
    const float* __restrict__ gt,
    const float* __restrict__ heatmap,
    float* __restrict__ ws)
{
    const int bj  = blockIdx.x;        // 0..511
    const int b   = bj >> 4;
    const int tid = threadIdx.x;

    // Stream this (b,j)'s 65536-float heatmap slice: 64 coalesced float4/thread.
    // Non-temporal (read-once): skip cache allocate. unroll 16 -> 16 NT loads
    // in flight per wave to cover full-HBM latency (no L2 assist on NT path).
    const f32x4* hm = (const f32x4*)(heatmap + (size_t)bj * HW);

    float best = -3.402823466e+38f;
    int   bidx = 0x7fffffff;

    #pragma unroll 16
    for (int it = 0; it < HW / 4 / TPB; ++it) {
        const int v4   = it * TPB + tid;
        const f32x4 v  = __builtin_nontemporal_load(&hm[v4]);
        const int base = v4 * 4;
        // Strict '>' keeps the earliest index within this thread's
        // monotonically-increasing scan order (JAX argmax = first occurrence).
        if (v.x > best) { best = v.x; bidx = base;     }
        if (v.y > best) { best = v.y; bidx = base + 1; }
        if (v.z > best) { best = v.z; bidx = base + 2; }
        if (v.w > best) { best = v.w; bidx = base + 3; }
    }

    // Wave-64 shuffle reduce; ties -> smaller flat index.
    #pragma unroll
    for (int off = 32; off > 0; off >>= 1) {
        const float ov = __shfl_down(best, off);
        const int   oi = __shfl_down(bidx, off);
        if (ov > best || (ov == best && oi < bidx)) { best = ov; bidx = oi; }
    }

    __shared__ float sval[4];
    __shared__ int   sidx[4];
    const int wave = tid >> 6;
    const int lane = tid & 63;
    if (lane == 0) { sval[wave] = best; sidx[wave] = bidx; }
    __syncthreads();

    if (tid == 0) {
        #pragma unroll
        for (int w = 1; w < 4; ++w) {
            if (sval[w] > best || (sval[w] == best && sidx[w] < bidx)) {
                best = sval[w]; bidx = sidx[w];
            }
        }
        float loss = 0.0f;
        if (best == 1.0f) {
            const int x = bidx >> 8;    // idx / 256
            const int y = bidx & 255;   // idx % 256
            const float* gp = gt + (size_t)bj * Cn;
            #pragma unroll
            for (int c = 0; c < Cn; ++c) {
                const float pv = pred[(((size_t)b * Cn + c) * Hq + x) * Wq + y];
                const float d  = pv - gp[c];
                loss += d * d;
            }
        }
        ws[bj] = loss;   // written unconditionally -> no ws init needed
    }
}

__global__ void labelloss_sum_kernel(const float* __restrict__ ws,
                                     float* __restrict__ out)
{
    const int b = threadIdx.x;
    if (b < Bq) {
        float s = 0.0f;
        #pragma unroll
        for (int j = 0; j < Jq; ++j) s += ws[b * Jq + j];
        out[b] = s;      // all 32 outputs written unconditionally
    }
}

extern "C" void kernel_launch(void* const* d_in, const int* in_sizes, int n_in,
                              void* d_out, int out_size, void* d_ws, size_t ws_size,
                              hipStream_t stream)
{
    const float* pred    = (const float*)d_in[0];   // (B, C, H, W) f32
    const float* gt      = (const float*)d_in[1];   // (B, J, C)   f32
    const float* heatmap = (const float*)d_in[2];   // (B, J, H, W) f32
    float* out = (float*)d_out;                     // (B,) f32
    float* ws  = (float*)d_ws;                      // NBJ floats of scratch

    labelloss_argmax_kernel<<<NBJ, TPB, 0, stream>>>(pred, gt, heatmap, ws);
    labelloss_sum_kernel<<<1, 64, 0, stream>>>(ws, out);
}

// Round 10
// 25.399 us; speedup vs baseline: 1.0323x; 1.0323x over previous
//
#include <hip/hip_runtime.h>

#define Bq 32
#define Jq 16
#define Hq 256
#define Wq 256
#define Cn 7
#define HW (Hq * Wq)          // 65536 per (b,j)
#define NBJ (Bq * Jq)         // 512 blocks, one per (b,j)
#define TPB 256

typedef float f32x4 __attribute__((ext_vector_type(4)));

__global__ __launch_bounds__(TPB) void labelloss_argmax_kernel(
    const float* __restrict__ pred,
    const float* __restrict__ gt,
    const float* __restrict__ heatmap,
    float* __restrict__ ws)
{
    const int bj  = blockIdx.x;        // 0..511
    const int b   = bj >> 4;
    const int tid = threadIdx.x;

    // Stream this (b,j)'s 65536-float heatmap slice: 64 coalesced float4/thread.
    // Non-temporal (read-once): skip cache allocate. unroll 8 is the measured
    // sweet spot (4 = 26.9us, 8 = 25.2us, 16 = 26.2us): 8 NT loads in flight
    // per wave covers HBM latency without VGPR/issue-tail overhead.
    const f32x4* hm = (const f32x4*)(heatmap + (size_t)bj * HW);

    float best = -3.402823466e+38f;
    int   bidx = 0x7fffffff;

    #pragma unroll 8
    for (int it = 0; it < HW / 4 / TPB; ++it) {
        const int v4   = it * TPB + tid;
        const f32x4 v  = __builtin_nontemporal_load(&hm[v4]);
        const int base = v4 * 4;
        // Strict '>' keeps the earliest index within this thread's
        // monotonically-increasing scan order (JAX argmax = first occurrence).
        if (v.x > best) { best = v.x; bidx = base;     }
        if (v.y > best) { best = v.y; bidx = base + 1; }
        if (v.z > best) { best = v.z; bidx = base + 2; }
        if (v.w > best) { best = v.w; bidx = base + 3; }
    }

    // Wave-64 shuffle reduce; ties -> smaller flat index.
    #pragma unroll
    for (int off = 32; off > 0; off >>= 1) {
        const float ov = __shfl_down(best, off);
        const int   oi = __shfl_down(bidx, off);
        if (ov > best || (ov == best && oi < bidx)) { best = ov; bidx = oi; }
    }

    __shared__ float sval[4];
    __shared__ int   sidx[4];
    const int wave = tid >> 6;
    const int lane = tid & 63;
    if (lane == 0) { sval[wave] = best; sidx[wave] = bidx; }
    __syncthreads();

    if (tid == 0) {
        #pragma unroll
        for (int w = 1; w < 4; ++w) {
            if (sval[w] > best || (sval[w] == best && sidx[w] < bidx)) {
                best = sval[w]; bidx = sidx[w];
            }
        }
        float loss = 0.0f;
        if (best == 1.0f) {
            const int x = bidx >> 8;    // idx / 256
            const int y = bidx & 255;   // idx % 256
            const float* gp = gt + (size_t)bj * Cn;
            #pragma unroll
            for (int c = 0; c < Cn; ++c) {
                const float pv = pred[(((size_t)b * Cn + c) * Hq + x) * Wq + y];
                const float d  = pv - gp[c];
                loss += d * d;
            }
        }
        ws[bj] = loss;   // written unconditionally -> no ws init needed
    }
}

__global__ void labelloss_sum_kernel(const float* __restrict__ ws,
                                     float* __restrict__ out)
{
    const int b = threadIdx.x;
    if (b < Bq) {
        float s = 0.0f;
        #pragma unroll
        for (int j = 0; j < Jq; ++j) s += ws[b * Jq + j];
        out[b] = s;      // all 32 outputs written unconditionally
    }
}

extern "C" void kernel_launch(void* const* d_in, const int* in_sizes, int n_in,
                              void* d_out, int out_size, void* d_ws, size_t ws_size,
                              hipStream_t stream)
{
    const float* pred    = (const float*)d_in[0];   // (B, C, H, W) f32
    const float* gt      = (const float*)d_in[1];   // (B, J, C)   f32
    const float* heatmap = (const float*)d_in[2];   // (B, J, H, W) f32
    float* out = (float*)d_out;                     // (B,) f32
    float* ws  = (float*)d_ws;                      // NBJ floats of scratch

    labelloss_argmax_kernel<<<NBJ, TPB, 0, stream>>>(pred, gt, heatmap, ws);
    labelloss_sum_kernel<<<1, 64, 0, stream>>>(ws, out);
}